// Round 4
// baseline (437.909 us; speedup 1.0000x reference)
//
#include <hip/hip_runtime.h>

typedef unsigned short u16;
typedef __bf16 bf16x8 __attribute__((ext_vector_type(8)));
typedef float f32x4 __attribute__((ext_vector_type(4)));
typedef u16 u16x4 __attribute__((ext_vector_type(4)));

#define LOG2E 1.44269504089f
#define SOFF 16.0f  // constant softmax offset (normalization is global, any constant works)

__device__ __forceinline__ f32x4 mfma16(bf16x8 a, bf16x8 b, f32x4 c) {
    return __builtin_amdgcn_mfma_f32_16x16x32_bf16(a, b, c, 0, 0, 0);
}
__device__ __forceinline__ u16 f2bf(float f) {  // RNE fp32 -> bf16
    union { float f; unsigned u; } x; x.f = f;
    unsigned r = x.u + 0x7FFFu + ((x.u >> 16) & 1u);
    return (u16)(r >> 16);
}
// async global->LDS, 16B per lane, wave-uniform LDS base + lane*16
__device__ __forceinline__ void gload_lds16(const u16* g, u16* l) {
    __builtin_amdgcn_global_load_lds((const __attribute__((address_space(1))) unsigned int*)g,
                                     (__attribute__((address_space(3))) unsigned int*)l, 16, 0, 0);
}

// ---------------- prep kernels ----------------

__global__ __launch_bounds__(256) void f32_to_bf16_kernel(const float* __restrict__ in, u16* __restrict__ out) {
    const int i = (blockIdx.x * 256 + threadIdx.x) * 8;
    f32x4 a = *(const f32x4*)(in + i);
    f32x4 b = *(const f32x4*)(in + i + 4);
    u16x4 o0, o1;
#pragma unroll
    for (int k = 0; k < 4; ++k) { o0[k] = f2bf(a[k]); o1[k] = f2bf(b[k]); }
    *(u16x4*)(out + i) = o0;
    *(u16x4*)(out + i + 4) = o1;
}

// in fp32 [R,C] -> out bf16 [C,R]
__global__ __launch_bounds__(256) void transpose_f32_bf16(const float* __restrict__ in, u16* __restrict__ out,
                                                          int R, int C) {
    __shared__ float t[32][33];
    const int tx = threadIdx.x & 31, ty = threadIdx.x >> 5;
    const int c0 = blockIdx.x * 32, r0 = blockIdx.y * 32;
#pragma unroll
    for (int k = 0; k < 4; ++k) t[ty + k * 8][tx] = in[(r0 + ty + k * 8) * C + c0 + tx];
    __syncthreads();
#pragma unroll
    for (int k = 0; k < 4; ++k) out[(c0 + ty + k * 8) * R + r0 + tx] = f2bf(t[tx][ty + k * 8]);
}

// 4x fused 512x512 transposes (wq,wk,wv,wo)
__global__ __launch_bounds__(256) void transpose4_f32_bf16(
    const float* __restrict__ w0, const float* __restrict__ w1,
    const float* __restrict__ w2, const float* __restrict__ w3,
    u16* __restrict__ o0, u16* __restrict__ o1, u16* __restrict__ o2, u16* __restrict__ o3) {
    __shared__ float t[32][33];
    const int z = blockIdx.z;
    const float* in = z == 0 ? w0 : (z == 1 ? w1 : (z == 2 ? w2 : w3));
    u16* out = z == 0 ? o0 : (z == 1 ? o1 : (z == 2 ? o2 : o3));
    const int tx = threadIdx.x & 31, ty = threadIdx.x >> 5;
    const int c0 = blockIdx.x * 32, r0 = blockIdx.y * 32;
#pragma unroll
    for (int k = 0; k < 4; ++k) t[ty + k * 8][tx] = in[(r0 + ty + k * 8) * 512 + c0 + tx];
    __syncthreads();
#pragma unroll
    for (int k = 0; k < 4; ++k) out[(c0 + ty + k * 8) * 512 + r0 + tx] = f2bf(t[tx][ty + k * 8]);
}

__global__ void count_nz(const int* __restrict__ pk, float* __restrict__ nzf) {
    __shared__ int red[256];
    int c = 0;
    for (int i = threadIdx.x; i < 1024; i += 256) c += (pk[i] != 0) ? 1 : 0;
    red[threadIdx.x] = c;
    __syncthreads();
    for (int s = 128; s > 0; s >>= 1) {
        if (threadIdx.x < s) red[threadIdx.x] += red[threadIdx.x + s];
        __syncthreads();
    }
    if (threadIdx.x == 0) nzf[0] = (float)red[0];
}

// padneg[b,s]: -SOFF if unmasked, huge-negative if masked (exp2 -> exact 0)
__global__ __launch_bounds__(256) void pad_extract(const float* __restrict__ mask, float* __restrict__ padneg) {
    const int i = blockIdx.x * 256 + threadIdx.x;  // 4096
    const int b = i >> 10, s = i & 1023;
    const float m = mask[((size_t)((b << 10) + s)) * 1024 + s];
    padneg[i] = (m > 0.5f) ? -1.5e9f : -SOFF;
}

// ---------------- GEMM: C[M,N] = A[M,K](bf16) * Bt[N,K]^T(bf16) ----------------
// global_load_lds staging (16B/lane), BK=64, XOR-swizzled LDS (chunk ^= row&7) to kill
// the 16-way ds_read_b128 bank conflicts (stride 128B). 4 waves in 2x2.
// MODE 0: fused QKV -> q:[B,H,S,D] bf16, k scaled LOG2E/8, v -> vT:[B,H,D,S] bf16  (N=1536)
// MODE 1: fp32 out + bias
// MODE 2: bf16 out + bias + relu
// MODE 3: fp32 out, no bias, K-split over blockIdx.z (z=0 -> dst0, z=1 -> dst1)
template <int BM, int BN, int MODE>
__global__ __launch_bounds__(256) void gemm_bf16(
    const u16* __restrict__ A,
    const u16* __restrict__ Bt0, const u16* __restrict__ Bt1, const u16* __restrict__ Bt2,
    const float* __restrict__ bias0, const float* __restrict__ bias1, const float* __restrict__ bias2,
    void* __restrict__ dst0, void* __restrict__ dst1, void* __restrict__ dst2,
    const int K, const int N) {
    constexpr int BK = 64;
    constexpr int WM = BM / 2, WN = BN / 2, MI = WM / 16, NI = WN / 16;
    __shared__ u16 lA[BM * BK];
    __shared__ u16 lB[BN * BK];
    const int tid = threadIdx.x;
    const int w = tid >> 6, lane = tid & 63, q = lane >> 4, ln = lane & 15;
    const int wm = w >> 1, wn = w & 1;
    const int n0 = blockIdx.x * BN, m0 = blockIdx.y * BM;
    const int rr = lane >> 3;                 // row within an 8-row staging group
    const int cs = ((lane & 7) ^ rr) * 8;     // swizzled k-offset (8 bf16 = 16B chunk)

    const u16* Bt;
    const float* bias;
    int nb, sel = 0;
    if (MODE == 0) {
        sel = n0 >> 9;
        Bt = sel == 0 ? Bt0 : (sel == 1 ? Bt1 : Bt2);
        bias = sel == 0 ? bias0 : (sel == 1 ? bias1 : bias2);
        nb = n0 & 511;
    } else {
        Bt = Bt0; bias = bias0; nb = n0;
    }
    int kbeg = 0, kend = K;
    if (MODE == 3) { const int kh = K >> 1; kbeg = blockIdx.z * kh; kend = kbeg + kh; }

    const f32x4 vzero = {0.f, 0.f, 0.f, 0.f};
    f32x4 acc[MI][NI];
#pragma unroll
    for (int i = 0; i < MI; ++i)
#pragma unroll
        for (int j = 0; j < NI; ++j) acc[i][j] = vzero;

    const int swa = ln & 7;  // fragment-read swizzle key (row&7 == ln&7)
    for (int k0 = kbeg; k0 < kend; k0 += BK) {
        const u16* Ag = A + (size_t)m0 * K + k0;
        const u16* Bg = Bt + (size_t)nb * K + k0;
#pragma unroll
        for (int c = 0; c < BM / 32; ++c) {
            const int r = (w * (BM / 32) + c) * 8;
            gload_lds16(Ag + (size_t)(r + rr) * K + cs, &lA[r * BK]);
        }
#pragma unroll
        for (int c = 0; c < BN / 32; ++c) {
            const int r = (w * (BN / 32) + c) * 8;
            gload_lds16(Bg + (size_t)(r + rr) * K + cs, &lB[r * BK]);
        }
        __syncthreads();
#pragma unroll
        for (int kb = 0; kb < 2; ++kb) {
            bf16x8 af[MI], bfr[NI];
#pragma unroll
            for (int mi = 0; mi < MI; ++mi)
                af[mi] = *(const bf16x8*)&lA[(wm * WM + mi * 16 + ln) * BK + ((((kb << 2) + q) ^ swa) << 3)];
#pragma unroll
            for (int ni = 0; ni < NI; ++ni)
                bfr[ni] = *(const bf16x8*)&lB[(wn * WN + ni * 16 + ln) * BK + ((((kb << 2) + q) ^ swa) << 3)];
#pragma unroll
            for (int mi = 0; mi < MI; ++mi)
#pragma unroll
                for (int ni = 0; ni < NI; ++ni) acc[mi][ni] = mfma16(af[mi], bfr[ni], acc[mi][ni]);
        }
        __syncthreads();
    }

    const float scl = (MODE == 0 && sel == 1) ? 0.125f * LOG2E : 1.0f;
#pragma unroll
    for (int mi = 0; mi < MI; ++mi) {
#pragma unroll
        for (int ni = 0; ni < NI; ++ni) {
            const int col = n0 + wn * WN + ni * 16 + ln;
            const float bv = (MODE == 3) ? 0.f : bias[MODE == 0 ? (col & 511) : col];
#pragma unroll
            for (int r = 0; r < 4; ++r) {
                const int row = m0 + wm * WM + mi * 16 + q * 4 + r;
                const float v = (acc[mi][ni][r] + bv) * scl;
                if (MODE == 0) {
                    const int cc = col & 511, hh = cc >> 6, dd = cc & 63;
                    const int bb = row >> 10, ss = row & 1023;
                    if (sel < 2) {
                        u16* dq = (u16*)(sel == 0 ? dst0 : dst1);
                        dq[(((bb << 3) + hh) * 1024 + ss) * 64 + dd] = f2bf(v);
                    } else {  // v written transposed: [B,H,D,S]
                        ((u16*)dst2)[(((bb << 3) + hh) * 64 + dd) * 1024 + ss] = f2bf(v);
                    }
                } else if (MODE == 1) {
                    ((float*)dst0)[(size_t)row * N + col] = v;
                } else if (MODE == 2) {
                    ((u16*)dst0)[(size_t)row * N + col] = f2bf(fmaxf(v, 0.f));
                } else {
                    float* d = (float*)(blockIdx.z == 0 ? dst0 : dst1);
                    d[(size_t)row * N + col] = v;
                }
            }
        }
    }
}

// ---------------- flash attention, constant-offset softmax (no online max) ----------------
// Kb (pre-scaled LOG2E/8), Qb: [B,H,S,64] bf16.  VT: [B,H,64,S] bf16.  padneg: [B,S] fp32.
// p = exp2(qk*log2e/8 + fmin(pi,pj)); masked -> exactly 0. Chunk ck covers j in [ck*256, +256).
#define PSTR 68
__global__ __launch_bounds__(256) void flash_kernel(
    const u16* __restrict__ Kb, const u16* __restrict__ Qb, const u16* __restrict__ VT,
    const float* __restrict__ padneg,
    float* __restrict__ Ounc, float* __restrict__ lrowc) {
    __shared__ u16 P[4][16 * PSTR];
    const int blk = blockIdx.x, ck = blockIdx.y;  // ck in {0..3}
    const int it = blk & 15, bh = blk >> 4, b = bh >> 3;
    const int i0 = it << 6;
    const int tid = threadIdx.x;
    const int w = tid >> 6, lane = tid & 63, q = lane >> 4, ln = lane & 15;

    const u16* Ka = Kb + ((bh << 10) + i0 + (w << 4) + ln) * 64;
    const bf16x8 af0 = *(const bf16x8*)(Ka + q * 8);
    const bf16x8 af1 = *(const bf16x8*)(Ka + 32 + q * 8);
    const u16* Qbase = Qb + (bh << 10) * 64;
    const u16* Vbase = VT + (bh << 6) * 1024;
    const float* pn = padneg + (b << 10);
    float pi[4];
#pragma unroll
    for (int r = 0; r < 4; ++r) pi[r] = pn[i0 + (w << 4) + (q << 2) + r];

    float lsum[4] = {0.f, 0.f, 0.f, 0.f};
    const f32x4 vzero = {0.f, 0.f, 0.f, 0.f};
    f32x4 acc[4] = {vzero, vzero, vzero, vzero};
    u16* Pw = &P[w][0];

    for (int jt4 = 0; jt4 < 4; ++jt4) {
        const int j0 = (ck << 8) + (jt4 << 6);
#pragma unroll
        for (int jt = 0; jt < 4; ++jt) {
            const float pj = pn[j0 + (jt << 4) + ln];
            const u16* Qp = Qbase + (j0 + (jt << 4) + ln) * 64 + q * 8;
            bf16x8 b0 = *(const bf16x8*)Qp;
            bf16x8 b1 = *(const bf16x8*)(Qp + 32);
            f32x4 c = vzero;
            c = mfma16(af0, b0, c);
            c = mfma16(af1, b1, c);
#pragma unroll
            for (int r = 0; r < 4; ++r) {
                const float pe = exp2f(c[r] + fminf(pi[r], pj));
                lsum[r] += pe;
                Pw[((q << 2) + r) * PSTR + (jt << 4) + ln] = f2bf(pe);
            }
        }
        // P (C-layout) -> A-operand layout via LDS (same wave, in-order LDS pipe)
        const bf16x8 pa0 = *(const bf16x8*)(Pw + ln * PSTR + q * 8);
        const bf16x8 pa1 = *(const bf16x8*)(Pw + ln * PSTR + 32 + q * 8);
#pragma unroll
        for (int ds = 0; ds < 4; ++ds) {
            const u16* Vp = Vbase + ((ds << 4) + ln) * 1024 + j0 + q * 8;
            bf16x8 v0 = *(const bf16x8*)Vp;
            bf16x8 v1 = *(const bf16x8*)(Vp + 32);
            acc[ds] = mfma16(pa0, v0, acc[ds]);
            acc[ds] = mfma16(pa1, v1, acc[ds]);
        }
    }
    const int t = (bh << 10) + i0 + (w << 4) + (q << 2);
    float* Oc = Ounc + ((size_t)ck << 21);
#pragma unroll
    for (int ds = 0; ds < 4; ++ds)
#pragma unroll
        for (int r = 0; r < 4; ++r) Oc[(size_t)(t + r) * 64 + (ds << 4) + ln] = acc[ds][r];
#pragma unroll
    for (int r = 0; r < 4; ++r) {
        float s = lsum[r];
#pragma unroll
        for (int o = 1; o < 16; o <<= 1) s += __shfl_xor(s, o);
        if (ln == 0) lrowc[(ck << 15) + t + r] = s;
    }
}

// per-(b,h): Zs[bh] = nz / sum_{c,i} l
__global__ __launch_bounds__(256) void combine_z(
    const float* __restrict__ lrowc, const float* __restrict__ nzf, float* __restrict__ Zs) {
    const int bh = blockIdx.x;
    const int tid = threadIdx.x, w = tid >> 6, lane = tid & 63;
    __shared__ float z4[4];
    float z = 0.f;
#pragma unroll
    for (int c = 0; c < 4; ++c)
        for (int i = tid; i < 1024; i += 256) z += lrowc[(c << 15) + (bh << 10) + i];
#pragma unroll
    for (int o = 32; o > 0; o >>= 1) z += __shfl_xor(z, o);
    if (lane == 0) z4[w] = z;
    __syncthreads();
    if (tid == 0) Zs[bh] = nzf[0] / (z4[0] + z4[1] + z4[2] + z4[3]);
}

// out = (sum of 4 Ounc chunks) * Zs[bh] -> o_bf16 [B,S,DM] (head regather)
__global__ __launch_bounds__(256) void scale_o(
    const float* __restrict__ Ounc, const float* __restrict__ Zs, u16* __restrict__ obf) {
    const int t = blockIdx.x * 4 + (threadIdx.x >> 6);
    const int lane = threadIdx.x & 63;
    const int bh = t >> 10, i = t & 1023, b = bh >> 3, h = bh & 7;
    float v = 0.f;
#pragma unroll
    for (int c = 0; c < 4; ++c) v += Ounc[((size_t)c << 21) + (size_t)t * 64 + lane];
    obf[((b << 10) + i) * 512 + (h << 6) + lane] = f2bf(v * Zs[bh]);
}

// out = LN(base + d1 [+ d2 + colbias]); writes fp32 and bf16. One wave per row of 512.
template <int ND>
__global__ __launch_bounds__(256) void ln_kernel(
    const float* __restrict__ base, const float* __restrict__ d1, const float* __restrict__ d2,
    const float* __restrict__ cb,
    const float* __restrict__ g, const float* __restrict__ bb,
    float* __restrict__ of32, u16* __restrict__ obf) {
    const int t = blockIdx.x * 4 + (threadIdx.x >> 6);
    const int lane = threadIdx.x & 63;
    const int off = t * 512 + lane * 8;
    f32x4 a0 = *(const f32x4*)(base + off);
    f32x4 a1 = *(const f32x4*)(base + off + 4);
    f32x4 e0 = *(const f32x4*)(d1 + off);
    f32x4 e1 = *(const f32x4*)(d1 + off + 4);
    float v[8];
#pragma unroll
    for (int k = 0; k < 4; ++k) { v[k] = a0[k] + e0[k]; v[k + 4] = a1[k] + e1[k]; }
    if (ND == 2) {
        f32x4 f0 = *(const f32x4*)(d2 + off);
        f32x4 f1v = *(const f32x4*)(d2 + off + 4);
        f32x4 c0 = *(const f32x4*)(cb + lane * 8);
        f32x4 c1 = *(const f32x4*)(cb + lane * 8 + 4);
#pragma unroll
        for (int k = 0; k < 4; ++k) { v[k] += f0[k] + c0[k]; v[k + 4] += f1v[k] + c1[k]; }
    }
    float s = 0.f;
#pragma unroll
    for (int k = 0; k < 8; ++k) s += v[k];
#pragma unroll
    for (int o = 32; o > 0; o >>= 1) s += __shfl_xor(s, o);
    const float mean = s * (1.f / 512.f);
    float vs = 0.f;
#pragma unroll
    for (int k = 0; k < 8; ++k) { const float d = v[k] - mean; vs += d * d; }
#pragma unroll
    for (int o = 32; o > 0; o >>= 1) vs += __shfl_xor(vs, o);
    const float r = rsqrtf(vs * (1.f / 512.f) + 1e-9f);
    f32x4 y0, y1;
    u16x4 o0, o1;
#pragma unroll
    for (int k = 0; k < 4; ++k) {
        const int c = lane * 8 + k;
        const float ya = (v[k] - mean) * r * g[c] + bb[c];
        y0[k] = ya; o0[k] = f2bf(ya);
        const int c2 = c + 4;
        const float yb = (v[k + 4] - mean) * r * g[c2] + bb[c2];
        y1[k] = yb; o1[k] = f2bf(yb);
    }
    *(f32x4*)(of32 + off) = y0;
    *(f32x4*)(of32 + off + 4) = y1;
    *(u16x4*)(obf + off) = o0;
    *(u16x4*)(obf + off + 4) = o1;
}

// ---------------- host ----------------

extern "C" void kernel_launch(void* const* d_in, const int* in_sizes, int n_in,
                              void* d_out, int out_size, void* d_ws, size_t ws_size,
                              hipStream_t stream) {
    const float* x = (const float*)d_in[0];
    const float* mask = (const float*)d_in[1];
    const int* protok = (const int*)d_in[2];
    const float* wq = (const float*)d_in[3]; const float* bq = (const float*)d_in[4];
    const float* wk = (const float*)d_in[5]; const float* bk = (const float*)d_in[6];
    const float* wv = (const float*)d_in[7]; const float* bv = (const float*)d_in[8];
    const float* wo = (const float*)d_in[9]; const float* bo = (const float*)d_in[10];
    const float* w1 = (const float*)d_in[11]; const float* b1 = (const float*)d_in[12];
    const float* w2 = (const float*)d_in[13]; const float* b2 = (const float*)d_in[14];
    const float* ln1g = (const float*)d_in[15]; const float* ln1b = (const float*)d_in[16];
    const float* ln2g = (const float*)d_in[17]; const float* ln2b = (const float*)d_in[18];

    char* p = (char*)d_ws;
    auto take = [&](size_t bytes) -> char* {
        char* r = p;
        p += (bytes + 255) & ~(size_t)255;
        return r;
    };
    u16* wqT = (u16*)take(512 * 512 * 2);
    u16* wkT = (u16*)take(512 * 512 * 2);
    u16* wvT = (u16*)take(512 * 512 * 2);
    u16* woT = (u16*)take(512 * 512 * 2);
    u16* w1T = (u16*)take(2048 * 512 * 2);
    u16* w2T = (u16*)take(512 * 2048 * 2);
    u16* hbf = (u16*)take(4096 * 512 * 2);
    float* hf32 = (float*)take(4096 * 512 * 4);
    u16* qb = (u16*)take(32 * 1024 * 64 * 2);
    u16* kb = (u16*)take(32 * 1024 * 64 * 2);
    u16* vT = (u16*)take(32 * 64 * 1024 * 2);
    float* Ounc = (float*)take(4ull * 32 * 1024 * 64 * 4);  // 4 chunks
    float* lrowc = (float*)take(4 * 32768 * 4);
    float* Zs = (float*)take(64 * 4);
    float* nzf = (float*)take(256);
    float* padneg = (float*)take(4096 * 4);
    u16* obf = (u16*)take(4096 * 512 * 2);
    float* attn = (float*)take(4096 * 512 * 4);
    float* out1f = (float*)take(4096 * 512 * 4);
    u16* out1bf = (u16*)take(4096 * 512 * 2);
    u16* f1 = (u16*)take(4096 * 2048 * 2);
    float* ffn0 = (float*)take(4096 * 512 * 4);
    float* ffn1 = (float*)take(4096 * 512 * 4);

    // prep
    f32_to_bf16_kernel<<<dim3(1024), 256, 0, stream>>>(x, hbf);
    transpose4_f32_bf16<<<dim3(16, 16, 4), 256, 0, stream>>>(wq, wk, wv, wo, wqT, wkT, wvT, woT);
    transpose_f32_bf16<<<dim3(64, 16), 256, 0, stream>>>(w1, w1T, 512, 2048);
    transpose_f32_bf16<<<dim3(16, 64), 256, 0, stream>>>(w2, w2T, 2048, 512);
    count_nz<<<dim3(1), 256, 0, stream>>>(protok, nzf);
    pad_extract<<<dim3(16), 256, 0, stream>>>(mask, padneg);

    const float* hin = x;
    for (int l = 0; l < 2; ++l) {
        // fused QKV projection: q -> [B,H,S,D]; k scaled LOG2E/8; v -> vT [B,H,D,S]
        gemm_bf16<128, 64, 0><<<dim3(24, 32), 256, 0, stream>>>(
            hbf, wqT, wkT, wvT, bq, bk, bv, qb, kb, vT, 512, 1536);
        // flash (Q/K swapped => computes A^T V), constant-offset softmax, 4 j-chunks
        flash_kernel<<<dim3(512, 4), 256, 0, stream>>>(kb, qb, vT, padneg, Ounc, lrowc);
        combine_z<<<dim3(32), 256, 0, stream>>>(lrowc, nzf, Zs);
        scale_o<<<dim3(8192), 256, 0, stream>>>(Ounc, Zs, obf);
        // output projection (fp32 out + bias)
        gemm_bf16<64, 64, 1><<<dim3(8, 64), 256, 0, stream>>>(
            obf, woT, woT, woT, bo, bo, bo, attn, attn, attn, 512, 512);
        // out1 = LN(h + attn)
        ln_kernel<1><<<dim3(1024), 256, 0, stream>>>(hin, attn, nullptr, nullptr, ln1g, ln1b, out1f, out1bf);
        // FFN1 (bias+relu, bf16 out)
        gemm_bf16<128, 64, 2><<<dim3(32, 32), 256, 0, stream>>>(
            out1bf, w1T, w1T, w1T, b1, b1, b1, f1, f1, f1, 512, 2048);
        // FFN2: K-split x2, fp32 partials, bias b2 folded into ln2
        gemm_bf16<128, 64, 3><<<dim3(8, 32, 2), 256, 0, stream>>>(
            f1, w2T, w2T, w2T, b2, b2, b2, ffn0, ffn1, ffn1, 2048, 512);
        // h' = LN(out1 + ffn0 + ffn1 + b2); final layer writes d_out
        float* hout = (l == 1) ? (float*)d_out : hf32;
        ln_kernel<2><<<dim3(1024), 256, 0, stream>>>(out1f, ffn0, ffn1, b2, ln2g, ln2b, hout, hbf);
        hin = hf32;
    }
}

// Round 5
// 356.764 us; speedup vs baseline: 1.2274x; 1.2274x over previous
//
#include <hip/hip_runtime.h>

typedef unsigned short u16;
typedef __bf16 bf16x8 __attribute__((ext_vector_type(8)));
typedef float f32x4 __attribute__((ext_vector_type(4)));
typedef u16 u16x4 __attribute__((ext_vector_type(4)));

#define LOG2E 1.44269504089f
#define SOFF 16.0f  // constant softmax offset (normalization is global, any constant works)

__device__ __forceinline__ f32x4 mfma16(bf16x8 a, bf16x8 b, f32x4 c) {
    return __builtin_amdgcn_mfma_f32_16x16x32_bf16(a, b, c, 0, 0, 0);
}
__device__ __forceinline__ u16 f2bf(float f) {  // RNE fp32 -> bf16
    union { float f; unsigned u; } x; x.f = f;
    unsigned r = x.u + 0x7FFFu + ((x.u >> 16) & 1u);
    return (u16)(r >> 16);
}
__device__ __forceinline__ float bf2f(u16 u) {
    union { unsigned u; float f; } x; x.u = ((unsigned)u) << 16;
    return x.f;
}
// async global->LDS, 16B per lane, wave-uniform LDS base + lane*16
__device__ __forceinline__ void gload_lds16(const u16* g, u16* l) {
    __builtin_amdgcn_global_load_lds((const __attribute__((address_space(1))) unsigned int*)g,
                                     (__attribute__((address_space(3))) unsigned int*)l, 16, 0, 0);
}

// ---------------- prep kernels ----------------

__global__ __launch_bounds__(256) void f32_to_bf16_kernel(const float* __restrict__ in, u16* __restrict__ out) {
    const int i = (blockIdx.x * 256 + threadIdx.x) * 8;
    f32x4 a = *(const f32x4*)(in + i);
    f32x4 b = *(const f32x4*)(in + i + 4);
    u16x4 o0, o1;
#pragma unroll
    for (int k = 0; k < 4; ++k) { o0[k] = f2bf(a[k]); o1[k] = f2bf(b[k]); }
    *(u16x4*)(out + i) = o0;
    *(u16x4*)(out + i + 4) = o1;
}

// in fp32 [R,C] -> out bf16 [C,R]
__global__ __launch_bounds__(256) void transpose_f32_bf16(const float* __restrict__ in, u16* __restrict__ out,
                                                          int R, int C) {
    __shared__ float t[32][33];
    const int tx = threadIdx.x & 31, ty = threadIdx.x >> 5;
    const int c0 = blockIdx.x * 32, r0 = blockIdx.y * 32;
#pragma unroll
    for (int k = 0; k < 4; ++k) t[ty + k * 8][tx] = in[(r0 + ty + k * 8) * C + c0 + tx];
    __syncthreads();
#pragma unroll
    for (int k = 0; k < 4; ++k) out[(c0 + ty + k * 8) * R + r0 + tx] = f2bf(t[tx][ty + k * 8]);
}

// 4x fused 512x512 transposes (wq,wk,wv,wo)
__global__ __launch_bounds__(256) void transpose4_f32_bf16(
    const float* __restrict__ w0, const float* __restrict__ w1,
    const float* __restrict__ w2, const float* __restrict__ w3,
    u16* __restrict__ o0, u16* __restrict__ o1, u16* __restrict__ o2, u16* __restrict__ o3) {
    __shared__ float t[32][33];
    const int z = blockIdx.z;
    const float* in = z == 0 ? w0 : (z == 1 ? w1 : (z == 2 ? w2 : w3));
    u16* out = z == 0 ? o0 : (z == 1 ? o1 : (z == 2 ? o2 : o3));
    const int tx = threadIdx.x & 31, ty = threadIdx.x >> 5;
    const int c0 = blockIdx.x * 32, r0 = blockIdx.y * 32;
#pragma unroll
    for (int k = 0; k < 4; ++k) t[ty + k * 8][tx] = in[(r0 + ty + k * 8) * 512 + c0 + tx];
    __syncthreads();
#pragma unroll
    for (int k = 0; k < 4; ++k) out[(c0 + ty + k * 8) * 512 + r0 + tx] = f2bf(t[tx][ty + k * 8]);
}

__global__ void count_nz(const int* __restrict__ pk, float* __restrict__ nzf) {
    __shared__ int red[256];
    int c = 0;
    for (int i = threadIdx.x; i < 1024; i += 256) c += (pk[i] != 0) ? 1 : 0;
    red[threadIdx.x] = c;
    __syncthreads();
    for (int s = 128; s > 0; s >>= 1) {
        if (threadIdx.x < s) red[threadIdx.x] += red[threadIdx.x + s];
        __syncthreads();
    }
    if (threadIdx.x == 0) nzf[0] = (float)red[0];
}

// padneg[b,s]: -SOFF if unmasked, huge-negative if masked (exp2 -> exact 0)
__global__ __launch_bounds__(256) void pad_extract(const float* __restrict__ mask, float* __restrict__ padneg) {
    const int i = blockIdx.x * 256 + threadIdx.x;  // 4096
    const int b = i >> 10, s = i & 1023;
    const float m = mask[((size_t)((b << 10) + s)) * 1024 + s];
    padneg[i] = (m > 0.5f) ? -1.5e9f : -SOFF;
}

// ---------------- GEMM: C[M,N] = A[M,K](bf16) * Bt[N,K]^T(bf16) ----------------
// global_load_lds staging (16B/lane), BK=64, XOR-swizzled LDS (chunk ^= row&7). 4 waves 2x2.
// MODE 0: fused QKV -> q:[B,H,S,D] bf16, k scaled LOG2E/8, v -> vT:[B,H,D,S] bf16  (N=1536)
// MODE 1: fp32 out + bias
// MODE 2: bf16 out + bias + relu
// MODE 3: fp32 out, no bias, K-split over blockIdx.z (z=0 -> dst0, z=1 -> dst1)
template <int BM, int BN, int MODE>
__global__ __launch_bounds__(256) void gemm_bf16(
    const u16* __restrict__ A,
    const u16* __restrict__ Bt0, const u16* __restrict__ Bt1, const u16* __restrict__ Bt2,
    const float* __restrict__ bias0, const float* __restrict__ bias1, const float* __restrict__ bias2,
    void* __restrict__ dst0, void* __restrict__ dst1, void* __restrict__ dst2,
    const int K, const int N) {
    constexpr int BK = 64;
    constexpr int WM = BM / 2, WN = BN / 2, MI = WM / 16, NI = WN / 16;
    __shared__ u16 lA[BM * BK];
    __shared__ u16 lB[BN * BK];
    const int tid = threadIdx.x;
    const int w = tid >> 6, lane = tid & 63, q = lane >> 4, ln = lane & 15;
    const int wm = w >> 1, wn = w & 1;
    const int n0 = blockIdx.x * BN, m0 = blockIdx.y * BM;
    const int rr = lane >> 3;                 // row within an 8-row staging group
    const int cs = ((lane & 7) ^ rr) * 8;     // swizzled k-offset (8 bf16 = 16B chunk)

    const u16* Bt;
    const float* bias;
    int nb, sel = 0;
    if (MODE == 0) {
        sel = n0 >> 9;
        Bt = sel == 0 ? Bt0 : (sel == 1 ? Bt1 : Bt2);
        bias = sel == 0 ? bias0 : (sel == 1 ? bias1 : bias2);
        nb = n0 & 511;
    } else {
        Bt = Bt0; bias = bias0; nb = n0;
    }
    int kbeg = 0, kend = K;
    if (MODE == 3) { const int kh = K >> 1; kbeg = blockIdx.z * kh; kend = kbeg + kh; }

    const f32x4 vzero = {0.f, 0.f, 0.f, 0.f};
    f32x4 acc[MI][NI];
#pragma unroll
    for (int i = 0; i < MI; ++i)
#pragma unroll
        for (int j = 0; j < NI; ++j) acc[i][j] = vzero;

    const int swa = ln & 7;  // fragment-read swizzle key (row&7 == ln&7)
    for (int k0 = kbeg; k0 < kend; k0 += BK) {
        const u16* Ag = A + (size_t)m0 * K + k0;
        const u16* Bg = Bt + (size_t)nb * K + k0;
#pragma unroll
        for (int c = 0; c < BM / 32; ++c) {
            const int r = (w * (BM / 32) + c) * 8;
            gload_lds16(Ag + (size_t)(r + rr) * K + cs, &lA[r * BK]);
        }
#pragma unroll
        for (int c = 0; c < BN / 32; ++c) {
            const int r = (w * (BN / 32) + c) * 8;
            gload_lds16(Bg + (size_t)(r + rr) * K + cs, &lB[r * BK]);
        }
        __syncthreads();
#pragma unroll
        for (int kb = 0; kb < 2; ++kb) {
            bf16x8 af[MI], bfr[NI];
#pragma unroll
            for (int mi = 0; mi < MI; ++mi)
                af[mi] = *(const bf16x8*)&lA[(wm * WM + mi * 16 + ln) * BK + ((((kb << 2) + q) ^ swa) << 3)];
#pragma unroll
            for (int ni = 0; ni < NI; ++ni)
                bfr[ni] = *(const bf16x8*)&lB[(wn * WN + ni * 16 + ln) * BK + ((((kb << 2) + q) ^ swa) << 3)];
#pragma unroll
            for (int mi = 0; mi < MI; ++mi)
#pragma unroll
                for (int ni = 0; ni < NI; ++ni) acc[mi][ni] = mfma16(af[mi], bfr[ni], acc[mi][ni]);
        }
        __syncthreads();
    }

    const float scl = (MODE == 0 && sel == 1) ? 0.125f * LOG2E : 1.0f;
#pragma unroll
    for (int mi = 0; mi < MI; ++mi) {
#pragma unroll
        for (int ni = 0; ni < NI; ++ni) {
            const int col = n0 + wn * WN + ni * 16 + ln;
            const float bv = (MODE == 3) ? 0.f : bias[MODE == 0 ? (col & 511) : col];
#pragma unroll
            for (int r = 0; r < 4; ++r) {
                const int row = m0 + wm * WM + mi * 16 + q * 4 + r;
                const float v = (acc[mi][ni][r] + bv) * scl;
                if (MODE == 0) {
                    const int cc = col & 511, hh = cc >> 6, dd = cc & 63;
                    const int bb = row >> 10, ss = row & 1023;
                    if (sel < 2) {
                        u16* dq = (u16*)(sel == 0 ? dst0 : dst1);
                        dq[(((bb << 3) + hh) * 1024 + ss) * 64 + dd] = f2bf(v);
                    } else {  // v written transposed: [B,H,D,S]
                        ((u16*)dst2)[(((bb << 3) + hh) * 64 + dd) * 1024 + ss] = f2bf(v);
                    }
                } else if (MODE == 1) {
                    ((float*)dst0)[(size_t)row * N + col] = v;
                } else if (MODE == 2) {
                    ((u16*)dst0)[(size_t)row * N + col] = f2bf(fmaxf(v, 0.f));
                } else {
                    float* d = (float*)(blockIdx.z == 0 ? dst0 : dst1);
                    d[(size_t)row * N + col] = v;
                }
            }
        }
    }
}

// ---------------- flash attention: LDS-staged tiles, constant-offset softmax ----------------
// Kb (pre-scaled LOG2E/8), Qb: [B,H,S,64] bf16.  VT: [B,H,64,S] bf16.  padneg: [B,S] fp32.
// Q/V j-tiles staged once per block in LDS (global_load_lds, XOR swizzle), shared by 4 waves.
// Unnormalized O written in bf16 per chunk; chunk ck covers j in [ck*256, +256).
#define PSTR 68
__global__ __launch_bounds__(256) void flash_kernel(
    const u16* __restrict__ Kb, const u16* __restrict__ Qb, const u16* __restrict__ VT,
    const float* __restrict__ padneg,
    u16* __restrict__ Ounc, float* __restrict__ lrowc) {
    __shared__ u16 ldsQ[64 * 64];   // [j-local][d], row 128B, swizzled chunks
    __shared__ u16 ldsV[64 * 64];   // [d][j-local], row 128B, swizzled chunks
    __shared__ u16 P[4][16 * PSTR];
    const int blk = blockIdx.x, ck = blockIdx.y;  // ck in {0..3}
    const int it = blk & 15, bh = blk >> 4, b = bh >> 3;
    const int i0 = it << 6;
    const int tid = threadIdx.x;
    const int w = tid >> 6, lane = tid & 63, q = lane >> 4, ln = lane & 15;

    // K fragment (A operand) from global, once
    const u16* Ka = Kb + ((bh << 10) + i0 + (w << 4) + ln) * 64;
    const bf16x8 af0 = *(const bf16x8*)(Ka + q * 8);
    const bf16x8 af1 = *(const bf16x8*)(Ka + 32 + q * 8);
    const u16* Qbase = Qb + (bh << 10) * 64;
    const u16* Vbase = VT + (bh << 6) * 1024;
    const float* pn = padneg + (b << 10);
    float pi[4];
#pragma unroll
    for (int r = 0; r < 4; ++r) pi[r] = pn[i0 + (w << 4) + (q << 2) + r];

    float lsum[4] = {0.f, 0.f, 0.f, 0.f};
    const f32x4 vzero = {0.f, 0.f, 0.f, 0.f};
    f32x4 acc[4] = {vzero, vzero, vzero, vzero};
    u16* Pw = &P[w][0];

    const int srow = lane >> 3;                // staging: row within 8-row group
    const int scol = ((lane & 7) ^ srow) * 8;  // swizzled source 16B chunk
    const int sw = ln & 7;                     // fragment-read swizzle key
    const int half = w & 1;

    for (int js = 0; js < 4; ++js) {
        const int j0 = (ck << 8) + (js << 6);
        // stage Q tile (waves 0,1) and V tile (waves 2,3): 4 gload_lds16 each
        if (w < 2) {
            const u16* src = Qbase + (size_t)(j0 + half * 32) * 64;
#pragma unroll
            for (int c = 0; c < 4; ++c) {
                const int r = half * 32 + c * 8;
                gload_lds16(src + (size_t)(c * 8 + srow) * 64 + scol, &ldsQ[r * 64]);
            }
        } else {
            const u16* src = Vbase + (size_t)(half * 32) * 1024 + j0;
#pragma unroll
            for (int c = 0; c < 4; ++c) {
                const int r = half * 32 + c * 8;
                gload_lds16(src + (size_t)(c * 8 + srow) * 1024 + scol, &ldsV[r * 64]);
            }
        }
        __syncthreads();
#pragma unroll
        for (int jt = 0; jt < 4; ++jt) {
            const int jr = (jt << 4) + ln;
            const float pj = pn[j0 + jr];
            bf16x8 b0 = *(const bf16x8*)&ldsQ[jr * 64 + ((q ^ sw) << 3)];
            bf16x8 b1 = *(const bf16x8*)&ldsQ[jr * 64 + (((q + 4) ^ sw) << 3)];
            f32x4 c = vzero;
            c = mfma16(af0, b0, c);
            c = mfma16(af1, b1, c);
#pragma unroll
            for (int r = 0; r < 4; ++r) {
                const float pe = exp2f(c[r] + fminf(pi[r], pj));
                lsum[r] += pe;
                Pw[((q << 2) + r) * PSTR + (jt << 4) + ln] = f2bf(pe);
            }
        }
        // P (C-layout) -> A-operand layout via LDS (same wave, in-order LDS pipe)
        const bf16x8 pa0 = *(const bf16x8*)(Pw + ln * PSTR + q * 8);
        const bf16x8 pa1 = *(const bf16x8*)(Pw + ln * PSTR + 32 + q * 8);
#pragma unroll
        for (int ds = 0; ds < 4; ++ds) {
            const int vr = (ds << 4) + ln;
            bf16x8 v0 = *(const bf16x8*)&ldsV[vr * 64 + ((q ^ sw) << 3)];
            bf16x8 v1 = *(const bf16x8*)&ldsV[vr * 64 + (((q + 4) ^ sw) << 3)];
            acc[ds] = mfma16(pa0, v0, acc[ds]);
            acc[ds] = mfma16(pa1, v1, acc[ds]);
        }
        __syncthreads();
    }
    const int t = (bh << 10) + i0 + (w << 4) + (q << 2);
    u16* Oc = Ounc + ((size_t)ck << 21);
#pragma unroll
    for (int ds = 0; ds < 4; ++ds)
#pragma unroll
        for (int r = 0; r < 4; ++r) Oc[(size_t)(t + r) * 64 + (ds << 4) + ln] = f2bf(acc[ds][r]);
#pragma unroll
    for (int r = 0; r < 4; ++r) {
        float s = lsum[r];
#pragma unroll
        for (int o = 1; o < 16; o <<= 1) s += __shfl_xor(s, o);
        if (ln == 0) lrowc[(ck << 15) + t + r] = s;
    }
}

// per-(b,h): Zs[bh] = nz / sum_{c,i} l
__global__ __launch_bounds__(256) void combine_z(
    const float* __restrict__ lrowc, const float* __restrict__ nzf, float* __restrict__ Zs) {
    const int bh = blockIdx.x;
    const int tid = threadIdx.x, w = tid >> 6, lane = tid & 63;
    __shared__ float z4[4];
    float z = 0.f;
#pragma unroll
    for (int c = 0; c < 4; ++c)
        for (int i = tid; i < 1024; i += 256) z += lrowc[(c << 15) + (bh << 10) + i];
#pragma unroll
    for (int o = 32; o > 0; o >>= 1) z += __shfl_xor(z, o);
    if (lane == 0) z4[w] = z;
    __syncthreads();
    if (tid == 0) Zs[bh] = nzf[0] / (z4[0] + z4[1] + z4[2] + z4[3]);
}

// out = (sum of 4 bf16 Ounc chunks) * Zs[bh] -> o_bf16 [B,S,DM] (head regather)
__global__ __launch_bounds__(256) void scale_o(
    const u16* __restrict__ Ounc, const float* __restrict__ Zs, u16* __restrict__ obf) {
    const int t = blockIdx.x * 4 + (threadIdx.x >> 6);
    const int lane = threadIdx.x & 63;
    const int bh = t >> 10, i = t & 1023, b = bh >> 3, h = bh & 7;
    float v = 0.f;
#pragma unroll
    for (int c = 0; c < 4; ++c) v += bf2f(Ounc[((size_t)c << 21) + (size_t)t * 64 + lane]);
    obf[((b << 10) + i) * 512 + (h << 6) + lane] = f2bf(v * Zs[bh]);
}

// out = LN(base + d1 [+ d2 + colbias]); writes fp32 and bf16. One wave per row of 512.
template <int ND>
__global__ __launch_bounds__(256) void ln_kernel(
    const float* __restrict__ base, const float* __restrict__ d1, const float* __restrict__ d2,
    const float* __restrict__ cb,
    const float* __restrict__ g, const float* __restrict__ bb,
    float* __restrict__ of32, u16* __restrict__ obf) {
    const int t = blockIdx.x * 4 + (threadIdx.x >> 6);
    const int lane = threadIdx.x & 63;
    const int off = t * 512 + lane * 8;
    f32x4 a0 = *(const f32x4*)(base + off);
    f32x4 a1 = *(const f32x4*)(base + off + 4);
    f32x4 e0 = *(const f32x4*)(d1 + off);
    f32x4 e1 = *(const f32x4*)(d1 + off + 4);
    float v[8];
#pragma unroll
    for (int k = 0; k < 4; ++k) { v[k] = a0[k] + e0[k]; v[k + 4] = a1[k] + e1[k]; }
    if (ND == 2) {
        f32x4 f0 = *(const f32x4*)(d2 + off);
        f32x4 f1v = *(const f32x4*)(d2 + off + 4);
        f32x4 c0 = *(const f32x4*)(cb + lane * 8);
        f32x4 c1 = *(const f32x4*)(cb + lane * 8 + 4);
#pragma unroll
        for (int k = 0; k < 4; ++k) { v[k] += f0[k] + c0[k]; v[k + 4] += f1v[k] + c1[k]; }
    }
    float s = 0.f;
#pragma unroll
    for (int k = 0; k < 8; ++k) s += v[k];
#pragma unroll
    for (int o = 32; o > 0; o >>= 1) s += __shfl_xor(s, o);
    const float mean = s * (1.f / 512.f);
    float vs = 0.f;
#pragma unroll
    for (int k = 0; k < 8; ++k) { const float d = v[k] - mean; vs += d * d; }
#pragma unroll
    for (int o = 32; o > 0; o >>= 1) vs += __shfl_xor(vs, o);
    const float r = rsqrtf(vs * (1.f / 512.f) + 1e-9f);
    f32x4 y0, y1;
    u16x4 o0, o1;
#pragma unroll
    for (int k = 0; k < 4; ++k) {
        const int c = lane * 8 + k;
        const float ya = (v[k] - mean) * r * g[c] + bb[c];
        y0[k] = ya; o0[k] = f2bf(ya);
        const int c2 = c + 4;
        const float yb = (v[k + 4] - mean) * r * g[c2] + bb[c2];
        y1[k] = yb; o1[k] = f2bf(yb);
    }
    *(f32x4*)(of32 + off) = y0;
    *(f32x4*)(of32 + off + 4) = y1;
    *(u16x4*)(obf + off) = o0;
    *(u16x4*)(obf + off + 4) = o1;
}

// ---------------- host ----------------

extern "C" void kernel_launch(void* const* d_in, const int* in_sizes, int n_in,
                              void* d_out, int out_size, void* d_ws, size_t ws_size,
                              hipStream_t stream) {
    const float* x = (const float*)d_in[0];
    const float* mask = (const float*)d_in[1];
    const int* protok = (const int*)d_in[2];
    const float* wq = (const float*)d_in[3]; const float* bq = (const float*)d_in[4];
    const float* wk = (const float*)d_in[5]; const float* bk = (const float*)d_in[6];
    const float* wv = (const float*)d_in[7]; const float* bv = (const float*)d_in[8];
    const float* wo = (const float*)d_in[9]; const float* bo = (const float*)d_in[10];
    const float* w1 = (const float*)d_in[11]; const float* b1 = (const float*)d_in[12];
    const float* w2 = (const float*)d_in[13]; const float* b2 = (const float*)d_in[14];
    const float* ln1g = (const float*)d_in[15]; const float* ln1b = (const float*)d_in[16];
    const float* ln2g = (const float*)d_in[17]; const float* ln2b = (const float*)d_in[18];

    char* p = (char*)d_ws;
    auto take = [&](size_t bytes) -> char* {
        char* r = p;
        p += (bytes + 255) & ~(size_t)255;
        return r;
    };
    u16* wqT = (u16*)take(512 * 512 * 2);
    u16* wkT = (u16*)take(512 * 512 * 2);
    u16* wvT = (u16*)take(512 * 512 * 2);
    u16* woT = (u16*)take(512 * 512 * 2);
    u16* w1T = (u16*)take(2048 * 512 * 2);
    u16* w2T = (u16*)take(512 * 2048 * 2);
    u16* hbf = (u16*)take(4096 * 512 * 2);
    float* hf32 = (float*)take(4096 * 512 * 4);
    u16* qb = (u16*)take(32 * 1024 * 64 * 2);
    u16* kb = (u16*)take(32 * 1024 * 64 * 2);
    u16* vT = (u16*)take(32 * 64 * 1024 * 2);
    u16* Ounc = (u16*)take(4ull * 32 * 1024 * 64 * 2);  // 4 chunks, bf16
    float* lrowc = (float*)take(4 * 32768 * 4);
    float* Zs = (float*)take(64 * 4);
    float* nzf = (float*)take(256);
    float* padneg = (float*)take(4096 * 4);
    u16* obf = (u16*)take(4096 * 512 * 2);
    float* attn = (float*)take(4096 * 512 * 4);
    float* out1f = (float*)take(4096 * 512 * 4);
    u16* out1bf = (u16*)take(4096 * 512 * 2);
    u16* f1 = (u16*)take(4096 * 2048 * 2);
    float* ffn0 = (float*)take(4096 * 512 * 4);
    float* ffn1 = (float*)take(4096 * 512 * 4);

    // prep
    f32_to_bf16_kernel<<<dim3(1024), 256, 0, stream>>>(x, hbf);
    transpose4_f32_bf16<<<dim3(16, 16, 4), 256, 0, stream>>>(wq, wk, wv, wo, wqT, wkT, wvT, woT);
    transpose_f32_bf16<<<dim3(64, 16), 256, 0, stream>>>(w1, w1T, 512, 2048);
    transpose_f32_bf16<<<dim3(16, 64), 256, 0, stream>>>(w2, w2T, 2048, 512);
    count_nz<<<dim3(1), 256, 0, stream>>>(protok, nzf);
    pad_extract<<<dim3(16), 256, 0, stream>>>(mask, padneg);

    const float* hin = x;
    for (int l = 0; l < 2; ++l) {
        // fused QKV projection: q -> [B,H,S,D]; k scaled LOG2E/8; v -> vT [B,H,D,S]
        gemm_bf16<128, 64, 0><<<dim3(24, 32), 256, 0, stream>>>(
            hbf, wqT, wkT, wvT, bq, bk, bv, qb, kb, vT, 512, 1536);
        // flash (Q/K swapped => computes A^T V), LDS-staged tiles, 4 j-chunks
        flash_kernel<<<dim3(512, 4), 256, 0, stream>>>(kb, qb, vT, padneg, Ounc, lrowc);
        combine_z<<<dim3(32), 256, 0, stream>>>(lrowc, nzf, Zs);
        scale_o<<<dim3(8192), 256, 0, stream>>>(Ounc, Zs, obf);
        // output projection (fp32 out + bias)
        gemm_bf16<64, 64, 1><<<dim3(8, 64), 256, 0, stream>>>(
            obf, woT, woT, woT, bo, bo, bo, attn, attn, attn, 512, 512);
        // out1 = LN(h + attn)
        ln_kernel<1><<<dim3(1024), 256, 0, stream>>>(hin, attn, nullptr, nullptr, ln1g, ln1b, out1f, out1bf);
        // FFN1 (bias+relu, bf16 out)
        gemm_bf16<128, 64, 2><<<dim3(32, 32), 256, 0, stream>>>(
            out1bf, w1T, w1T, w1T, b1, b1, b1, f1, f1, f1, 512, 2048);
        // FFN2: K-split x2, fp32 partials, bias b2 folded into ln2
        gemm_bf16<128, 64, 3><<<dim3(8, 32, 2), 256, 0, stream>>>(
            f1, w2T, w2T, w2T, b2, b2, b2, ffn0, ffn1, ffn1, 2048, 512);
        // h' = LN(out1 + ffn0 + ffn1 + b2); final layer writes d_out
        float* hout = (l == 1) ? (float*)d_out : hf32;
        ln_kernel<2><<<dim3(1024), 256, 0, stream>>>(out1f, ffn0, ffn1, b2, ln2g, ln2b, hout, hbf);
        hin = hf32;
    }
}